// Round 7
// baseline (476.445 us; speedup 1.0000x reference)
//
#include <hip/hip_runtime.h>

// Problem constants
#define BN    2400   // B*N
#define NG    4      // groups
#define PIN   32     // in_points
#define DIM   256

// DTYPE: inputs fp32, output fp32. Internal ws bf16.
// R7: p2 kernels rewritten wave-per-(t,g), BARRIER-FREE. Each wave owns one
// (t,g): global->register MFMA fragments, LN/softmax via shfl butterflies,
// transposes via private per-wave LDS slices (in-order per-wave DS ops +
// explicit lgkmcnt(0) insurance). Gens/projections unchanged from R6.

typedef __attribute__((ext_vector_type(8))) short bf16x8;
typedef __attribute__((ext_vector_type(4))) short bf16x4;
typedef __attribute__((ext_vector_type(4))) float f32x4;

__device__ __forceinline__ float b2f(unsigned short u) {
    union { unsigned int i; float f; } v; v.i = ((unsigned int)u) << 16; return v.f;
}
__device__ __forceinline__ unsigned short f2b(float f) {
    union { float f; unsigned int i; } v; v.f = f;
    unsigned int x = v.i;
    return (unsigned short)((x + 0x7fffu + ((x >> 16) & 1u)) >> 16);  // RNE
}

// Wave-wide mean/rsqrt(var): butterfly over all 64 lanes.
__device__ __forceinline__ void wave_stats(float s, float q, float inv_n,
                                           float& mean, float& istd) {
    #pragma unroll
    for (int m = 1; m < 64; m <<= 1) {
        s += __shfl_xor(s, m, 64);
        q += __shfl_xor(q, m, 64);
    }
    mean = s * inv_n;
    float var = q * inv_n - mean * mean;
    istd = rsqrtf(var + 1e-5f);
}

// Block-wide stats (for gemm epilogue-free kernels: final_ln)
__device__ __forceinline__ void block_stats(float s, float q, float* sRed, int tid,
                                            float inv_n, float& mean, float& istd) {
    #pragma unroll
    for (int off = 32; off > 0; off >>= 1) {
        s += __shfl_down(s, off, 64);
        q += __shfl_down(q, off, 64);
    }
    if ((tid & 63) == 0) { sRed[(tid >> 6) * 2] = s; sRed[(tid >> 6) * 2 + 1] = q; }
    __syncthreads();
    if (tid == 0) {
        float ts = 0.f, tq = 0.f;
        for (int w = 0; w < 4; ++w) { ts += sRed[2 * w]; tq += sRed[2 * w + 1]; }
        float m = ts * inv_n;
        float var = tq * inv_n - m * m;
        sRed[8] = m; sRed[9] = rsqrtf(var + 1e-5f);
    }
    __syncthreads();
    mean = sRed[8]; istd = sRed[9];
}

// ---------------------------------------------------------------------------
// Weight prep A: fp32 -> bf16 with row permutation (g,c,d)->(g,d,c) + bias perm.
// ---------------------------------------------------------------------------
__global__ __launch_bounds__(256) void prep_perm_kernel(
    const float* __restrict__ w, const float* __restrict__ b,
    unsigned short* __restrict__ wOut, float* __restrict__ bOut)
{
    const int row_o = blockIdx.x * 4 + (threadIdx.x >> 6);
    const int lane = threadIdx.x & 63;
    const int g = row_o >> 12, d = (row_o >> 6) & 63, c = row_o & 63;
    const int row_i = (g << 12) + c * 64 + d;
    const float4 x = *(const float4*)(w + (size_t)row_i * 256 + lane * 4);
    bf16x4 pk;
    pk[0] = (short)f2b(x.x); pk[1] = (short)f2b(x.y);
    pk[2] = (short)f2b(x.z); pk[3] = (short)f2b(x.w);
    *(bf16x4*)(wOut + (size_t)row_o * 256 + lane * 4) = pk;
    if (lane == 0) bOut[row_o] = b[row_i];
}

// ---------------------------------------------------------------------------
// Weight prep B: flat fp32 -> bf16 convert, up to 3 tensors via blockIdx.y.
// ---------------------------------------------------------------------------
__global__ __launch_bounds__(256) void prep_flat_kernel(
    const float* __restrict__ a0, unsigned short* __restrict__ o0, int n0,
    const float* __restrict__ a1, unsigned short* __restrict__ o1, int n1,
    const float* __restrict__ a2, unsigned short* __restrict__ o2, int n2)
{
    const float* src; unsigned short* dst; int n;
    if (blockIdx.y == 0)      { src = a0; dst = o0; n = n0; }
    else if (blockIdx.y == 1) { src = a1; dst = o1; n = n1; }
    else                      { src = a2; dst = o2; n = n2; }
    const int idx = (blockIdx.x * 256 + threadIdx.x) * 8;
    if (idx >= n) return;
    float4 x0 = ((const float4*)(src + idx))[0];
    float4 x1 = ((const float4*)(src + idx))[1];
    bf16x8 v;
    v[0]=(short)f2b(x0.x); v[1]=(short)f2b(x0.y); v[2]=(short)f2b(x0.z); v[3]=(short)f2b(x0.w);
    v[4]=(short)f2b(x1.x); v[5]=(short)f2b(x1.y); v[6]=(short)f2b(x1.z); v[7]=(short)f2b(x1.w);
    *(bf16x8*)(dst + idx) = v;
}

// Bias copy fp32->fp32.
__global__ __launch_bounds__(256) void copy_bias_kernel(
    const float* __restrict__ a0, float* __restrict__ o0,
    const float* __restrict__ a1, float* __restrict__ o1)
{
    const int i = blockIdx.x * 256 + threadIdx.x;
    if (blockIdx.y == 0) o0[i] = a0[i]; else o1[i] = a1[i];
}

// ---------------------------------------------------------------------------
// NT GEMM: C(MxN) = A(MxK) * W(NxK)^T (+bias), all-bf16 in.
// Tile 64x64, padded LDS, 4 waves x (2x2) MFMA 16x16x32_bf16.
// OUT_MODE 0: bf16 out (+fp32 bias). OUT_MODE 2: fp32 split-K partial.
// ---------------------------------------------------------------------------
template<int OUT_MODE>
__global__ __launch_bounds__(256) void gemm_nt_kernel(
    const unsigned short* __restrict__ A,
    const unsigned short* __restrict__ W,
    const float* __restrict__ bias,
    void* __restrict__ Cout,
    int M, int N, int ldK, int kLen)
{
    __shared__ short sA[64][72];
    __shared__ short sB[64][72];

    const int m0 = blockIdx.x * 64;
    const int n0 = blockIdx.y * 64;
    const int tid = threadIdx.x;
    const int lane = tid & 63;
    const int wave = tid >> 6;
    const int l16 = lane & 15;
    const int quad = lane >> 4;
    const int wr = (wave >> 1) * 32;
    const int wc = (wave & 1) * 32;

    const int lr = tid >> 2;
    const int lc = (tid & 3) * 16;

    f32x4 acc[2][2] = {};

    const int kbase = blockIdx.z * kLen;
    for (int k0 = kbase; k0 < kbase + kLen; k0 += 64) {
        {
            const int gr = m0 + lr;
            bf16x8 a0 = {}, a1 = {};
            if (gr < M) {
                const unsigned short* ap = A + (size_t)gr * ldK + k0 + lc;
                a0 = ((const bf16x8*)ap)[0];
                a1 = ((const bf16x8*)ap)[1];
            }
            *(bf16x8*)(&sA[lr][lc])     = a0;
            *(bf16x8*)(&sA[lr][lc + 8]) = a1;
            const unsigned short* wp = W + (size_t)(n0 + lr) * ldK + k0 + lc;
            *(bf16x8*)(&sB[lr][lc])     = ((const bf16x8*)wp)[0];
            *(bf16x8*)(&sB[lr][lc + 8]) = ((const bf16x8*)wp)[1];
        }
        __syncthreads();
        #pragma unroll
        for (int ks = 0; ks < 64; ks += 32) {
            bf16x8 a0 = *(const bf16x8*)(&sA[wr + l16][ks + quad * 8]);
            bf16x8 a1 = *(const bf16x8*)(&sA[wr + 16 + l16][ks + quad * 8]);
            bf16x8 b0 = *(const bf16x8*)(&sB[wc + l16][ks + quad * 8]);
            bf16x8 b1 = *(const bf16x8*)(&sB[wc + 16 + l16][ks + quad * 8]);
            acc[0][0] = __builtin_amdgcn_mfma_f32_16x16x32_bf16(a0, b0, acc[0][0], 0, 0, 0);
            acc[0][1] = __builtin_amdgcn_mfma_f32_16x16x32_bf16(a0, b1, acc[0][1], 0, 0, 0);
            acc[1][0] = __builtin_amdgcn_mfma_f32_16x16x32_bf16(a1, b0, acc[1][0], 0, 0, 0);
            acc[1][1] = __builtin_amdgcn_mfma_f32_16x16x32_bf16(a1, b1, acc[1][1], 0, 0, 0);
        }
        __syncthreads();
    }

    #pragma unroll
    for (int s = 0; s < 2; ++s) {
        #pragma unroll
        for (int u = 0; u < 2; ++u) {
            const int col = n0 + wc + u * 16 + l16;
            const float bv = (OUT_MODE == 0 && bias) ? bias[col] : 0.0f;
            #pragma unroll
            for (int r = 0; r < 4; ++r) {
                const int row = m0 + wr + s * 16 + quad * 4 + r;
                if (row < M) {
                    const float val = acc[s][u][r] + bv;
                    if (OUT_MODE == 0) {
                        ((unsigned short*)Cout)[(size_t)row * N + col] = f2b(val);
                    } else {
                        float* o = (float*)Cout + (size_t)blockIdx.z * M * N;
                        o[(size_t)row * N + col] = val;
                    }
                }
            }
        }
    }
}

// ---------------------------------------------------------------------------
// Phase 2 reg — wave-per-(t,g), barrier-free.
// fMS = relu(LN2d(S @ relu(LN2d(f @ M))))
// Y1 row (20480) = [M^T (g*4096 + d*64 + c) | S (16384 + g*1024 + o*32 + p)]
// ---------------------------------------------------------------------------
__global__ __launch_bounds__(256) void p2_reg_kernel(
    const float* __restrict__ feats,           // (BN,G,32,64) fp32
    const unsigned short* __restrict__ Y1,     // (BN,20480) bf16
    unsigned short* __restrict__ FMS)          // (BN,8192)  bf16: g*2048+o*64+d
{
    const int t = blockIdx.x;
    const int tid = threadIdx.x;
    const int g = tid >> 6, lane = tid & 63;
    const int l16 = lane & 15, quad = lane >> 4;

    __shared__ __attribute__((aligned(16))) short X1T_s[NG][64][40];
    short (*X1T)[40] = X1T_s[g];

    // A-frags: f (fp32 -> bf16), layout A[m=l16-row][k=quad*8..]
    const float* fp = feats + (size_t)(t * NG + g) * 2048;
    bf16x8 fa[2][2];
    #pragma unroll
    for (int mt = 0; mt < 2; ++mt)
        #pragma unroll
        for (int ks = 0; ks < 2; ++ks) {
            const float* p = fp + (mt * 16 + l16) * 64 + ks * 32 + quad * 8;
            float4 x0 = ((const float4*)p)[0];
            float4 x1 = ((const float4*)p)[1];
            bf16x8 v;
            v[0]=(short)f2b(x0.x); v[1]=(short)f2b(x0.y); v[2]=(short)f2b(x0.z); v[3]=(short)f2b(x0.w);
            v[4]=(short)f2b(x1.x); v[5]=(short)f2b(x1.y); v[6]=(short)f2b(x1.z); v[7]=(short)f2b(x1.w);
            fa[mt][ks] = v;
        }
    // B-frags: Mt [d][c] direct from Y1
    const unsigned short* mp = Y1 + (size_t)t * 20480 + g * 4096;
    bf16x8 mb[4][2];
    #pragma unroll
    for (int nt = 0; nt < 4; ++nt)
        #pragma unroll
        for (int ks = 0; ks < 2; ++ks)
            mb[nt][ks] = *(const bf16x8*)(mp + (nt * 16 + l16) * 64 + ks * 32 + quad * 8);

    f32x4 accA[2][4] = {};
    #pragma unroll
    for (int ks = 0; ks < 2; ++ks)
        #pragma unroll
        for (int mt = 0; mt < 2; ++mt)
            #pragma unroll
            for (int nt = 0; nt < 4; ++nt)
                accA[mt][nt] = __builtin_amdgcn_mfma_f32_16x16x32_bf16(
                    fa[mt][ks], mb[nt][ks], accA[mt][nt], 0, 0, 0);

    float ls = 0.f, lq = 0.f;
    #pragma unroll
    for (int mt = 0; mt < 2; ++mt)
        #pragma unroll
        for (int nt = 0; nt < 4; ++nt)
            #pragma unroll
            for (int r = 0; r < 4; ++r) { float v = accA[mt][nt][r]; ls += v; lq += v * v; }
    float mean, istd;
    wave_stats(ls, lq, 1.0f / 2048.0f, mean, istd);

    // relu -> X1T [d][p] (C-layout row p=mt*16+quad*4+r, col d=nt*16+l16)
    #pragma unroll
    for (int nt = 0; nt < 4; ++nt)
        #pragma unroll
        for (int mt = 0; mt < 2; ++mt) {
            bf16x4 pk;
            #pragma unroll
            for (int r = 0; r < 4; ++r) {
                float y = (accA[mt][nt][r] - mean) * istd;
                pk[r] = (short)f2b(y > 0.f ? y : 0.f);
            }
            *(bf16x4*)(&X1T[nt * 16 + l16][mt * 16 + quad * 4]) = pk;
        }
    __builtin_amdgcn_s_waitcnt(0xc07f);   // lgkmcnt(0): writes visible to own-wave reads

    // Stage B: X2 = S @ X1 (K=32)
    const unsigned short* sp = Y1 + (size_t)t * 20480 + 16384 + g * 1024;
    bf16x8 sa[2], xb[4];
    #pragma unroll
    for (int mt = 0; mt < 2; ++mt)
        sa[mt] = *(const bf16x8*)(sp + (mt * 16 + l16) * 32 + quad * 8);
    #pragma unroll
    for (int nt = 0; nt < 4; ++nt)
        xb[nt] = *(const bf16x8*)(&X1T[nt * 16 + l16][quad * 8]);

    f32x4 accB[2][4] = {};
    #pragma unroll
    for (int mt = 0; mt < 2; ++mt)
        #pragma unroll
        for (int nt = 0; nt < 4; ++nt)
            accB[mt][nt] = __builtin_amdgcn_mfma_f32_16x16x32_bf16(
                sa[mt], xb[nt], accB[mt][nt], 0, 0, 0);

    ls = 0.f; lq = 0.f;
    #pragma unroll
    for (int mt = 0; mt < 2; ++mt)
        #pragma unroll
        for (int nt = 0; nt < 4; ++nt)
            #pragma unroll
            for (int r = 0; r < 4; ++r) { float v = accB[mt][nt][r]; ls += v; lq += v * v; }
    wave_stats(ls, lq, 1.0f / 2048.0f, mean, istd);

    unsigned short* outp = FMS + (size_t)t * 8192 + g * 2048;
    #pragma unroll
    for (int mt = 0; mt < 2; ++mt)
        #pragma unroll
        for (int r = 0; r < 4; ++r) {
            const int o = mt * 16 + quad * 4 + r;
            #pragma unroll
            for (int nt = 0; nt < 4; ++nt) {
                float y = (accB[mt][nt][r] - mean) * istd;
                outp[o * 64 + nt * 16 + l16] = f2b(y > 0.f ? y : 0.f);
            }
        }
}

// ---------------------------------------------------------------------------
// Phase 2 cls — wave-per-(t,g), barrier-free.
// v = relu(LN2d(f@vW)); k = kw·v^T + kb; sc = softmax(q@k/8); fc = relu(LN2d(sc@v))
// Per-wave LDS: vT[64][40] + region B (vRM[32][72] overlaid by kT[32][40]+sSC[32][40])
// ---------------------------------------------------------------------------
__global__ __launch_bounds__(256) void p2_cls_kernel(
    const float* __restrict__ feats,
    const unsigned short* __restrict__ Y2,     // (BN,20480) bf16 [vW^T | q]
    const float* __restrict__ kwp,             // (128,64) fp32
    const float* __restrict__ kbp,             // (128) fp32
    unsigned short* __restrict__ FC)
{
    const int t = blockIdx.x;
    const int tid = threadIdx.x;
    const int g = tid >> 6, lane = tid & 63;
    const int l16 = lane & 15, quad = lane >> 4;

    __shared__ __attribute__((aligned(16))) short vT_s[NG][64][40];
    __shared__ __attribute__((aligned(16))) short B2_s[NG][2560];
    short (*vT)[40] = vT_s[g];
    short* vRM = B2_s[g];            // v row-major [p][72]
    short* kT  = B2_s[g];            // k^T [p][40]  (overlays vRM after it's dead)
    short* sSC = B2_s[g] + 1280;     // sc [o][40]   (overlays vRM tail)

    // ---- stage 1: v = relu(LN2d(f @ vW)) ----
    const float* fp = feats + (size_t)(t * NG + g) * 2048;
    bf16x8 fa[2][2];
    #pragma unroll
    for (int mt = 0; mt < 2; ++mt)
        #pragma unroll
        for (int ks = 0; ks < 2; ++ks) {
            const float* p = fp + (mt * 16 + l16) * 64 + ks * 32 + quad * 8;
            float4 x0 = ((const float4*)p)[0];
            float4 x1 = ((const float4*)p)[1];
            bf16x8 v;
            v[0]=(short)f2b(x0.x); v[1]=(short)f2b(x0.y); v[2]=(short)f2b(x0.z); v[3]=(short)f2b(x0.w);
            v[4]=(short)f2b(x1.x); v[5]=(short)f2b(x1.y); v[6]=(short)f2b(x1.z); v[7]=(short)f2b(x1.w);
            fa[mt][ks] = v;
        }
    const unsigned short* vp = Y2 + (size_t)t * 20480 + g * 4096;
    bf16x8 vb[4][2];
    #pragma unroll
    for (int nt = 0; nt < 4; ++nt)
        #pragma unroll
        for (int ks = 0; ks < 2; ++ks)
            vb[nt][ks] = *(const bf16x8*)(vp + (nt * 16 + l16) * 64 + ks * 32 + quad * 8);

    f32x4 accA[2][4] = {};
    #pragma unroll
    for (int ks = 0; ks < 2; ++ks)
        #pragma unroll
        for (int mt = 0; mt < 2; ++mt)
            #pragma unroll
            for (int nt = 0; nt < 4; ++nt)
                accA[mt][nt] = __builtin_amdgcn_mfma_f32_16x16x32_bf16(
                    fa[mt][ks], vb[nt][ks], accA[mt][nt], 0, 0, 0);

    float ls = 0.f, lq = 0.f;
    #pragma unroll
    for (int mt = 0; mt < 2; ++mt)
        #pragma unroll
        for (int nt = 0; nt < 4; ++nt)
            #pragma unroll
            for (int r = 0; r < 4; ++r) { float v = accA[mt][nt][r]; ls += v; lq += v * v; }
    float mean, istd;
    wave_stats(ls, lq, 1.0f / 2048.0f, mean, istd);

    // write vT [d][p] (bf16x4) + vRM [p][d] (scalar)
    #pragma unroll
    for (int nt = 0; nt < 4; ++nt)
        #pragma unroll
        for (int mt = 0; mt < 2; ++mt) {
            bf16x4 pk;
            #pragma unroll
            for (int r = 0; r < 4; ++r) {
                float y = (accA[mt][nt][r] - mean) * istd;
                unsigned short u = f2b(y > 0.f ? y : 0.f);
                pk[r] = (short)u;
                vRM[(mt * 16 + quad * 4 + r) * 72 + nt * 16 + l16] = (short)u;
            }
            *(bf16x4*)(&vT[nt * 16 + l16][mt * 16 + quad * 4]) = pk;
        }
    __builtin_amdgcn_s_waitcnt(0xc07f);

    // ---- stage 2: k[i][p] = kw[i]·v[p] + kb[i] (K=64) ----
    bf16x8 ka[2][2], vr[2][2];
    #pragma unroll
    for (int it = 0; it < 2; ++it)
        #pragma unroll
        for (int ks = 0; ks < 2; ++ks) {
            const float* p = kwp + (size_t)g * 2048 + (it * 16 + l16) * 64 + ks * 32 + quad * 8;
            float4 x0 = ((const float4*)p)[0];
            float4 x1 = ((const float4*)p)[1];
            bf16x8 v;
            v[0]=(short)f2b(x0.x); v[1]=(short)f2b(x0.y); v[2]=(short)f2b(x0.z); v[3]=(short)f2b(x0.w);
            v[4]=(short)f2b(x1.x); v[5]=(short)f2b(x1.y); v[6]=(short)f2b(x1.z); v[7]=(short)f2b(x1.w);
            ka[it][ks] = v;
        }
    #pragma unroll
    for (int pt = 0; pt < 2; ++pt)
        #pragma unroll
        for (int ks = 0; ks < 2; ++ks)
            vr[pt][ks] = *(const bf16x8*)(vRM + (pt * 16 + l16) * 72 + ks * 32 + quad * 8);

    f32x4 accK[2][2] = {};
    #pragma unroll
    for (int ks = 0; ks < 2; ++ks)
        #pragma unroll
        for (int it = 0; it < 2; ++it)
            #pragma unroll
            for (int pt = 0; pt < 2; ++pt)
                accK[it][pt] = __builtin_amdgcn_mfma_f32_16x16x32_bf16(
                    ka[it][ks], vr[pt][ks], accK[it][pt], 0, 0, 0);

    // kb + write kT [p][i] (overlays vRM — its reads are already consumed)
    #pragma unroll
    for (int it = 0; it < 2; ++it) {
        float kbv[4];
        #pragma unroll
        for (int r = 0; r < 4; ++r) kbv[r] = kbp[g * 32 + it * 16 + quad * 4 + r];
        #pragma unroll
        for (int pt = 0; pt < 2; ++pt) {
            bf16x4 pk;
            #pragma unroll
            for (int r = 0; r < 4; ++r) pk[r] = (short)f2b(accK[it][pt][r] + kbv[r]);
            *(bf16x4*)(&kT[(pt * 16 + l16) * 40 + it * 16 + quad * 4]) = pk;
        }
    }
    __builtin_amdgcn_s_waitcnt(0xc07f);

    // ---- stage 3: logits = q@k/8, softmax over p ----
    bf16x8 qa[2], kb_[2];
    #pragma unroll
    for (int ot = 0; ot < 2; ++ot)
        qa[ot] = *(const bf16x8*)(Y2 + (size_t)t * 20480 + 16384 + g * 1024
                                  + (ot * 16 + l16) * 32 + quad * 8);
    #pragma unroll
    for (int pt = 0; pt < 2; ++pt)
        kb_[pt] = *(const bf16x8*)(kT + (pt * 16 + l16) * 40 + quad * 8);

    f32x4 accL[2][2] = {};
    #pragma unroll
    for (int ot = 0; ot < 2; ++ot)
        #pragma unroll
        for (int pt = 0; pt < 2; ++pt)
            accL[ot][pt] = __builtin_amdgcn_mfma_f32_16x16x32_bf16(
                qa[ot], kb_[pt], accL[ot][pt], 0, 0, 0);

    #pragma unroll
    for (int ot = 0; ot < 2; ++ot)
        #pragma unroll
        for (int r = 0; r < 4; ++r) {
            float a0 = accL[ot][0][r] * 0.125f, a1 = accL[ot][1][r] * 0.125f;
            float mx = fmaxf(a0, a1);
            #pragma unroll
            for (int m = 1; m < 16; m <<= 1) mx = fmaxf(mx, __shfl_xor(mx, m, 64));
            a0 = __expf(a0 - mx); a1 = __expf(a1 - mx);
            float sum = a0 + a1;
            #pragma unroll
            for (int m = 1; m < 16; m <<= 1) sum += __shfl_xor(sum, m, 64);
            const float inv_s = 1.0f / sum;
            const int o = ot * 16 + quad * 4 + r;
            sSC[o * 40 + l16]      = (short)f2b(a0 * inv_s);
            sSC[o * 40 + 16 + l16] = (short)f2b(a1 * inv_s);
        }
    __builtin_amdgcn_s_waitcnt(0xc07f);

    // ---- stage 4: fc = relu(LN2d(sc @ v)) (K=32) ----
    bf16x8 sa[2], vtb[4];
    #pragma unroll
    for (int mt = 0; mt < 2; ++mt)
        sa[mt] = *(const bf16x8*)(sSC + (mt * 16 + l16) * 40 + quad * 8);
    #pragma unroll
    for (int nt = 0; nt < 4; ++nt)
        vtb[nt] = *(const bf16x8*)(&vT[nt * 16 + l16][quad * 8]);

    f32x4 accB[2][4] = {};
    #pragma unroll
    for (int mt = 0; mt < 2; ++mt)
        #pragma unroll
        for (int nt = 0; nt < 4; ++nt)
            accB[mt][nt] = __builtin_amdgcn_mfma_f32_16x16x32_bf16(
                sa[mt], vtb[nt], accB[mt][nt], 0, 0, 0);

    ls = 0.f; lq = 0.f;
    #pragma unroll
    for (int mt = 0; mt < 2; ++mt)
        #pragma unroll
        for (int nt = 0; nt < 4; ++nt)
            #pragma unroll
            for (int r = 0; r < 4; ++r) { float v = accB[mt][nt][r]; ls += v; lq += v * v; }
    wave_stats(ls, lq, 1.0f / 2048.0f, mean, istd);

    unsigned short* outp = FC + (size_t)t * 8192 + g * 2048;
    #pragma unroll
    for (int mt = 0; mt < 2; ++mt)
        #pragma unroll
        for (int r = 0; r < 4; ++r) {
            const int o = mt * 16 + quad * 4 + r;
            #pragma unroll
            for (int nt = 0; nt < 4; ++nt) {
                float y = (accB[mt][nt][r] - mean) * istd;
                outp[o * 64 + nt * 16 + l16] = f2b(y > 0.f ? y : 0.f);
            }
        }
}

// ---------------------------------------------------------------------------
// Final: reduce split-K partials, residual add, affine LN over 256, fp32 out.
// ---------------------------------------------------------------------------
__global__ __launch_bounds__(256) void final_ln_kernel(
    const float* __restrict__ qv,
    const float* __restrict__ MSP,   // (8, BN, 256) fp32 partials
    const float* __restrict__ CLP,
    const float* __restrict__ Wv_b,
    const float* __restrict__ Wv2_b,
    const float* __restrict__ lnA_w,
    const float* __restrict__ lnA_b,
    const float* __restrict__ lnB_w,
    const float* __restrict__ lnB_b,
    float* __restrict__ out)
{
    __shared__ float sRed[16];
    const int t = blockIdx.x;
    const int br = blockIdx.y;
    const int c = threadIdx.x;
    const float* P = br ? CLP : MSP;
    const float* bias = br ? Wv2_b : Wv_b;
    const float* lw = br ? lnB_w : lnA_w;
    const float* lb = br ? lnB_b : lnA_b;

    float x = qv[t * 256 + c] + bias[c];
    #pragma unroll
    for (int s = 0; s < 8; ++s) x += P[(size_t)s * (BN * 256) + t * 256 + c];

    float mean, istd;
    block_stats(x, x * x, sRed, c, 1.0f / 256.0f, mean, istd);
    out[(size_t)br * (BN * 256) + t * 256 + c] = (x - mean) * istd * lw[c] + lb[c];
}

// ---------------------------------------------------------------------------
extern "C" void kernel_launch(void* const* d_in, const int* in_sizes, int n_in,
                              void* d_out, int out_size, void* d_ws, size_t ws_size,
                              hipStream_t stream) {
    const float* feats = (const float*)d_in[0];
    const float* qv    = (const float*)d_in[1];
    const float* m_w   = (const float*)d_in[7];
    const float* m_b   = (const float*)d_in[8];
    const float* s_w   = (const float*)d_in[9];
    const float* s_b   = (const float*)d_in[10];
    const float* q_w   = (const float*)d_in[11];
    const float* q_b   = (const float*)d_in[12];
    const float* v_w   = (const float*)d_in[13];
    const float* v_b   = (const float*)d_in[14];
    const float* k_w   = (const float*)d_in[15];
    const float* k_b   = (const float*)d_in[16];
    const float* Wv_w  = (const float*)d_in[17];
    const float* Wv_b  = (const float*)d_in[18];
    const float* Wv2_w = (const float*)d_in[19];
    const float* Wv2_b = (const float*)d_in[20];
    const float* lnA_w = (const float*)d_in[21];
    const float* lnA_b = (const float*)d_in[22];
    const float* lnB_w = (const float*)d_in[23];
    const float* lnB_b = (const float*)d_in[24];

    char* ws = (char*)d_ws;
    // Workspace (176.9 MB peak):
    //  [0, 98.3M)       Y1 (fused gen out, 2400x20480 bf16) -> later MSP/CLP/WvB
    //  [98.3M, 137.6M)  FMS
    //  [137.6M, 176.9M) FC; transient preps live here until p2_cls
    const size_t OFF_Y1  = 0;
    const size_t OFF_FMS = 98304000;
    const size_t OFF_FC  = 137625600;

    unsigned short* Y1  = (unsigned short*)(ws + OFF_Y1);
    unsigned short* FMS = (unsigned short*)(ws + OFF_FMS);
    unsigned short* FC  = (unsigned short*)(ws + OFF_FC);
    unsigned short* W1   = (unsigned short*)(ws + OFF_FC);               // [m_wP | s_wB]
    unsigned short* W2   = (unsigned short*)(ws + OFF_FC + 10485760);    // [v_wP | q_wB]
    unsigned short* qv_B = (unsigned short*)(ws + OFF_FC + 20971520);
    float* b1 = (float*)(ws + OFF_FC + 22200320);                        // [m_bP | s_b]
    float* b2 = (float*)(ws + OFF_FC + 22282240);                        // [v_bP | q_b]
    float* MSP = (float*)(ws + 0);
    float* CLP = (float*)(ws + 19660800);
    unsigned short* WvB  = (unsigned short*)(ws + 39321600);
    unsigned short* Wv2B = (unsigned short*)(ws + 43515904);

    const dim3 blk(256);
    // preps
    prep_perm_kernel<<<4096, blk, 0, stream>>>(m_w, m_b, W1, b1);
    prep_perm_kernel<<<4096, blk, 0, stream>>>(v_w, v_b, W2, b2);
    prep_flat_kernel<<<dim3(512, 3), blk, 0, stream>>>(
        s_w, W1 + 16384 * 256, 4096 * 256,
        q_w, W2 + 16384 * 256, 4096 * 256,
        qv,  qv_B,             BN * 256);
    copy_bias_kernel<<<dim3(16, 2), blk, 0, stream>>>(s_b, b1 + 16384, q_b, b2 + 16384);
    // reg branch: fused M+S generator (N=20480), then p2
    gemm_nt_kernel<0><<<dim3(38, 320), blk, 0, stream>>>(qv_B, W1, b1, Y1, BN, 20480, 256, 256);
    p2_reg_kernel<<<BN, blk, 0, stream>>>(feats, Y1, FMS);
    // cls branch (reuse Y1)
    gemm_nt_kernel<0><<<dim3(38, 320), blk, 0, stream>>>(qv_B, W2, b2, Y1, BN, 20480, 256, 256);
    p2_cls_kernel<<<BN, blk, 0, stream>>>(feats, Y1, k_w, k_b, FC);
    // projections: bf16 weights into dead Y1 region, 64-tile splitK=8
    prep_flat_kernel<<<dim3(1024, 2), blk, 0, stream>>>(
        Wv_w, WvB, 256 * 8192, Wv2_w, Wv2B, 256 * 8192, nullptr, nullptr, 0);
    gemm_nt_kernel<2><<<dim3(38, 4, 8), blk, 0, stream>>>(FMS, WvB,  nullptr, MSP, BN, 256, 8192, 1024);
    gemm_nt_kernel<2><<<dim3(38, 4, 8), blk, 0, stream>>>(FC,  Wv2B, nullptr, CLP, BN, 256, 8192, 1024);
    final_ln_kernel<<<dim3(BN, 2), blk, 0, stream>>>(qv, MSP, CLP, Wv_b, Wv2_b,
                                                     lnA_w, lnA_b, lnB_w, lnB_b,
                                                     (float*)d_out);
}